// Round 3
// baseline (987.345 us; speedup 1.0000x reference)
//
#include <hip/hip_runtime.h>
#include <hip/hip_bf16.h>

// EmbeddingCrossAttention on MI355X (gfx950). f32 in/out, bf16 MFMA compute.
//
// softmax over single kv slot == 1  =>  ctx = v  =>  everything is affine:
//   t = text@Wt^T+bt ; a = audio@Wa^T+ba
//   t_ctx = a@Wvo^T + bvo      (Wvo = Wo.Wv, bvo = Wo.bv + bo)   [V GEMM folded away]
//   logit_t = t@Wgt1^T + a@(Wgt2.Wvo)^T + (bgt + Wgt2.bvo)       [CTX not a GEMM operand]
//   refined_t = g*t + (1-g)*t_ctx, g = sigmoid(logit_t)          (same for audio, swapped)
//
// Memory discipline (round-2 failed by overflowing ws and corrupting the
// harness's pristine input copies — ws usage now ~92 MB):
//   ws: X=[t;a] bf16 (64MB) | folded bf16 weights (~24.6MB) | f32 biases (12KB)
//   d_out: text_b/audio_b bf16 scratch (58.7MB, dead before ctx GEMMs), then
//          t_ctx/a_ctx f32 written AT final output offsets; gate kernels do a
//          private-tile in-place RMW (read ctx[m,n], write refined[m,n]).

typedef __attribute__((ext_vector_type(8))) short short8;
typedef __attribute__((ext_vector_type(4))) float floatx4;

__device__ __forceinline__ float bf2f(__hip_bfloat16 x) { return __bfloat162float(x); }

__device__ __forceinline__ void gl_lds16(const void* g, void* l) {
  __builtin_amdgcn_global_load_lds(
      (const __attribute__((address_space(1))) unsigned int*)g,
      (__attribute__((address_space(3))) unsigned int*)l,
      16, 0, 0);
}

// Strided f32 -> bf16 convert. One row per blockIdx.y, 4 cols per thread.
__global__ __launch_bounds__(256)
void cvt_kernel(const float* __restrict__ src, int sld,
                __hip_bfloat16* __restrict__ dst, int dld, int cols4) {
  const int r = blockIdx.y;
  const int c4 = blockIdx.x * 256 + threadIdx.x;
  if (c4 >= cols4) return;
  const float4 v = *(const float4*)(src + (size_t)r * sld + c4 * 4);
  union { __hip_bfloat16 h[4]; uint2 u; } o;
  o.h[0] = __float2bfloat16(v.x);
  o.h[1] = __float2bfloat16(v.y);
  o.h[2] = __float2bfloat16(v.z);
  o.h[3] = __float2bfloat16(v.w);
  *(uint2*)(dst + (size_t)r * dld + c4 * 4) = o.u;
}

// Transposed convert: dst[c][r] = bf16(src[r][c]), R=C=1024.
__global__ __launch_bounds__(256)
void cvt_t_kernel(const float* __restrict__ src, __hip_bfloat16* __restrict__ dst,
                  int R, int C) {
  __shared__ float tile[32][33];
  const int tx = threadIdx.x, ty = threadIdx.y;  // block (32, 8)
  const int bx = blockIdx.x * 32, by = blockIdx.y * 32;
#pragma unroll
  for (int i = 0; i < 32; i += 8)
    tile[ty + i][tx] = src[(size_t)(by + ty + i) * C + bx + tx];
  __syncthreads();
#pragma unroll
  for (int i = 0; i < 32; i += 8)
    dst[(size_t)(bx + ty + i) * R + by + tx] = __float2bfloat16(tile[tx][ty + i]);
}

// y[r] = sum_k W[r*ld + coff + k] * x[k] + b[r],  K = 1024. 4 rows/block.
__global__ __launch_bounds__(256)
void mv_kernel(const float* __restrict__ W, int ld, int coff,
               const float* __restrict__ x, const float* __restrict__ b,
               float* __restrict__ y) {
  const int lane = threadIdx.x & 63;
  const int row = blockIdx.x * 4 + (threadIdx.x >> 6);
  float acc = 0.f;
  for (int k = lane; k < 1024; k += 64)
    acc += W[(size_t)row * ld + coff + k] * x[k];
#pragma unroll
  for (int off = 32; off > 0; off >>= 1) acc += __shfl_down(acc, off);
  if (lane == 0) y[row] = acc + b[row];
}

// C = A @ W^T (+bias). A row-major bf16 (K-concat A1|A2 if K2>0), W bf16 (N x K).
// MODE 0: Cb[m*ldc+coff+n] = bf16(v)         (bias optional)
// MODE 1: Cf[m*ldc+n] = v (f32)
// MODE 2: gate RMW: g=sigmoid(v); ctx=Cf[m*ldc+n]; x=A1[m*K1+n];
//         Cf[m*ldc+n] = g*x + (1-g)*ctx
template <int MODE>
__global__ __launch_bounds__(256)
void gemm_bt_kernel(const __hip_bfloat16* __restrict__ A1,
                    const __hip_bfloat16* __restrict__ A2,
                    const __hip_bfloat16* __restrict__ W,
                    const float* __restrict__ bias,
                    __hip_bfloat16* __restrict__ Cb,
                    float* __restrict__ Cf,
                    int K1, int K2, int ldc, int coff) {
  constexpr int BM = 128, BN = 128, BK = 32;
  __shared__ __align__(16) __hip_bfloat16 lA[BM * BK];
  __shared__ __align__(16) __hip_bfloat16 lB[BN * BK];

  const int tid  = threadIdx.x;
  const int lane = tid & 63;
  const int wave = tid >> 6;
  const int wm = wave & 1;
  const int wn = wave >> 1;
  const int m0 = blockIdx.y * BM;
  const int n0 = blockIdx.x * BN;

  floatx4 acc[4][4];
#pragma unroll
  for (int i = 0; i < 4; ++i)
#pragma unroll
    for (int j = 0; j < 4; ++j) {
      floatx4 z = {0.f, 0.f, 0.f, 0.f};
      acc[i][j] = z;
    }

  const int K = K1 + K2;
  const int srow = tid >> 2;
  const int scol = (tid & 3) * 8;

  for (int k0 = 0; k0 < K; k0 += BK) {
    const __hip_bfloat16* srcA;
    int ldA;
    if (k0 < K1) { srcA = A1 + (size_t)m0 * K1 + k0;        ldA = K1; }
    else         { srcA = A2 + (size_t)m0 * K2 + (k0 - K1); ldA = K2; }
    const __hip_bfloat16* srcB = W + (size_t)n0 * K + k0;
#pragma unroll
    for (int p = 0; p < 2; ++p) {
      const int row = p * 64 + srow;
      gl_lds16(srcA + (size_t)row * ldA + scol, (char*)lA + p * 4096 + tid * 16);
      gl_lds16(srcB + (size_t)row * K + scol, (char*)lB + p * 4096 + tid * 16);
    }
    __syncthreads();

    short8 af[4], bfr[4];
    const int fr = lane & 15;
    const int fq = (lane >> 4) * 8;
#pragma unroll
    for (int i = 0; i < 4; ++i)
      af[i] = *(const short8*)((const short*)lA + (wm * 64 + i * 16 + fr) * BK + fq);
#pragma unroll
    for (int j = 0; j < 4; ++j)
      bfr[j] = *(const short8*)((const short*)lB + (wn * 64 + j * 16 + fr) * BK + fq);
#pragma unroll
    for (int i = 0; i < 4; ++i)
#pragma unroll
      for (int j = 0; j < 4; ++j)
        acc[i][j] = __builtin_amdgcn_mfma_f32_16x16x32_bf16(af[i], bfr[j], acc[i][j], 0, 0, 0);
    __syncthreads();
  }

  // D mapping: col = lane&15, row = (lane>>4)*4 + reg
  const int col = lane & 15;
  const int rq  = (lane >> 4) * 4;
#pragma unroll
  for (int j = 0; j < 4; ++j) {
    const int n = n0 + wn * 64 + j * 16 + col;
    const float bv = bias ? bias[n] : 0.f;
#pragma unroll
    for (int i = 0; i < 4; ++i) {
#pragma unroll
      for (int r = 0; r < 4; ++r) {
        const int m = m0 + wm * 64 + i * 16 + rq + r;
        const float v = acc[i][j][r] + bv;
        if (MODE == 0) {
          Cb[(size_t)m * ldc + coff + n] = __float2bfloat16(v);
        } else if (MODE == 1) {
          Cf[(size_t)m * ldc + n] = v;
        } else {
          const size_t oidx = (size_t)m * ldc + n;
          const float xv  = bf2f(A1[(size_t)m * K1 + n]);  // K1 == 1024 == N
          const float ctx = Cf[oidx];
          const float g = 1.f / (1.f + __expf(-v));
          Cf[oidx] = g * xv + (1.f - g) * ctx;
        }
      }
    }
  }
}

extern "C" void kernel_launch(void* const* d_in, const int* in_sizes, int n_in,
                              void* d_out, int out_size, void* d_ws, size_t ws_size,
                              hipStream_t stream) {
  (void)in_sizes; (void)n_in; (void)out_size; (void)ws_size;

  const float* text  = (const float*)d_in[0];
  const float* audio = (const float*)d_in[1];
  const float* Wt  = (const float*)d_in[2];
  const float* bt  = (const float*)d_in[3];
  const float* Wa  = (const float*)d_in[4];
  const float* ba  = (const float*)d_in[5];
  // d_in[6..9] = Wq,bq,Wk,bk: dead (softmax over single kv slot == 1)
  const float* Wv  = (const float*)d_in[10];
  const float* bv  = (const float*)d_in[11];
  const float* Wo  = (const float*)d_in[12];
  const float* bo  = (const float*)d_in[13];
  const float* Wgt = (const float*)d_in[14];
  const float* bgt = (const float*)d_in[15];
  const float* Wga = (const float*)d_in[16];
  const float* bga = (const float*)d_in[17];

  const size_t BE = 16384ull * 1024;
  const size_t M1 = 1024ull * 1024;
  float* out = (float*)d_out;

  // ws (total ~92 MB)
  __hip_bfloat16* p = (__hip_bfloat16*)d_ws;
  __hip_bfloat16* X       = p; p += 2 * BE;        // [t ; a]
  __hip_bfloat16* Wt_b    = p; p += 768ull * 1024;
  __hip_bfloat16* Wa_b    = p; p += M1;
  __hip_bfloat16* Wo_b    = p; p += M1;
  __hip_bfloat16* WvT_b   = p; p += M1;
  __hip_bfloat16* Wvo_b   = p; p += M1;
  __hip_bfloat16* WvoT_b  = p; p += M1;
  __hip_bfloat16* Wgt2_b  = p; p += M1;
  __hip_bfloat16* Wga2_b  = p; p += M1;
  __hip_bfloat16* Wgt_cat = p; p += 2 * M1;        // [Wgt1 | Wgt2.Wvo], ld 2048
  __hip_bfloat16* Wga_cat = p; p += 2 * M1;
  float* bvo  = (float*)p;
  float* bgtp = bvo + 1024;
  float* bgap = bvo + 2048;

  // d_out bf16 scratch (dead before ctx GEMMs overwrite d_out)
  __hip_bfloat16* text_b  = (__hip_bfloat16*)d_out;
  __hip_bfloat16* audio_b = text_b + 16384ull * 768;

  dim3 blk(256, 1, 1);

  // ---- converts ----
  cvt_kernel<<<dim3(1, 16384), blk, 0, stream>>>(text, 768, text_b, 768, 192);
  cvt_kernel<<<dim3(1, 16384), blk, 0, stream>>>(audio, 1024, audio_b, 1024, 256);
  cvt_kernel<<<dim3(1, 768), blk, 0, stream>>>(Wt, 1024, Wt_b, 1024, 256);
  cvt_kernel<<<dim3(1, 1024), blk, 0, stream>>>(Wa, 1024, Wa_b, 1024, 256);
  cvt_kernel<<<dim3(1, 1024), blk, 0, stream>>>(Wo, 1024, Wo_b, 1024, 256);
  cvt_t_kernel<<<dim3(32, 32), dim3(32, 8), 0, stream>>>(Wv, WvT_b, 1024, 1024);
  cvt_kernel<<<dim3(1, 1024), blk, 0, stream>>>(Wgt, 2048, Wgt_cat, 2048, 256);        // Wgt1
  cvt_kernel<<<dim3(1, 1024), blk, 0, stream>>>(Wgt + 1024, 2048, Wgt2_b, 1024, 256);  // Wgt2
  cvt_kernel<<<dim3(1, 1024), blk, 0, stream>>>(Wga, 2048, Wga_cat, 2048, 256);
  cvt_kernel<<<dim3(1, 1024), blk, 0, stream>>>(Wga + 1024, 2048, Wga2_b, 1024, 256);

  // ---- bias folds (f32) ----
  mv_kernel<<<dim3(256), blk, 0, stream>>>(Wo, 1024, 0, bv, bo, bvo);          // bvo = Wo.bv + bo
  mv_kernel<<<dim3(256), blk, 0, stream>>>(Wgt, 2048, 1024, bvo, bgt, bgtp);   // bgt' = Wgt2.bvo + bgt
  mv_kernel<<<dim3(256), blk, 0, stream>>>(Wga, 2048, 1024, bvo, bga, bgap);

  // ---- weight folds (1024^3 bf16 GEMMs) ----
  dim3 gw(8, 8);
  // Wvo[n,k]  = sum_m Wo[n,m] WvT[k,m]
  gemm_bt_kernel<0><<<gw, blk, 0, stream>>>(Wo_b, nullptr, WvT_b, nullptr, Wvo_b, nullptr, 1024, 0, 1024, 0);
  // WvoT[k,n] = sum_m WvT[k,m] Wo[n,m]
  gemm_bt_kernel<0><<<gw, blk, 0, stream>>>(WvT_b, nullptr, Wo_b, nullptr, WvoT_b, nullptr, 1024, 0, 1024, 0);
  // Wgt_cat[:,1024+k] = (Wgt2.Wvo)[n,k] = sum_m Wgt2[n,m] WvoT[k,m]
  gemm_bt_kernel<0><<<gw, blk, 0, stream>>>(Wgt2_b, nullptr, WvoT_b, nullptr, Wgt_cat, nullptr, 1024, 0, 2048, 1024);
  gemm_bt_kernel<0><<<gw, blk, 0, stream>>>(Wga2_b, nullptr, WvoT_b, nullptr, Wga_cat, nullptr, 1024, 0, 2048, 1024);

  // ---- main chain ----
  dim3 g1(8, 128);
  // t = text@Wt^T + bt ; a = audio@Wa^T + ba
  gemm_bt_kernel<0><<<g1, blk, 0, stream>>>(text_b, nullptr, Wt_b, bt, X, nullptr, 768, 0, 1024, 0);
  gemm_bt_kernel<0><<<g1, blk, 0, stream>>>(audio_b, nullptr, Wa_b, ba, X + BE, nullptr, 1024, 0, 1024, 0);
  // t_ctx = a@Wvo^T + bvo -> out[0..BE) ; a_ctx = t@Wvo^T + bvo -> out[BE..2BE)  (f32)
  gemm_bt_kernel<1><<<g1, blk, 0, stream>>>(X + BE, nullptr, Wvo_b, bvo, nullptr, out, 1024, 0, 1024, 0);
  gemm_bt_kernel<1><<<g1, blk, 0, stream>>>(X, nullptr, Wvo_b, bvo, nullptr, out + BE, 1024, 0, 1024, 0);
  // gates: logit = x@Wg1^T + other@(Wg2.Wvo)^T + bg' ; out = g*x + (1-g)*ctx (in-place RMW)
  gemm_bt_kernel<2><<<g1, blk, 0, stream>>>(X, X + BE, Wgt_cat, bgtp, nullptr, out, 1024, 1024, 1024, 0);
  gemm_bt_kernel<2><<<g1, blk, 0, stream>>>(X + BE, X, Wga_cat, bgap, nullptr, out + BE, 1024, 1024, 1024, 0);
}

// Round 4
// 966.981 us; speedup vs baseline: 1.0211x; 1.0211x over previous
//
#include <hip/hip_runtime.h>
#include <hip/hip_bf16.h>

// EmbeddingCrossAttention on MI355X (gfx950). f32 in/out, bf16 MFMA compute.
//
// softmax over single kv slot == 1  =>  ctx = v  =>  everything is affine:
//   t = text@Wt^T+bt ; a = audio@Wa^T+ba
//   t_ctx = a@Wvo^T + bvo            (Wvo = Wo.Wv, bvo = Wo.bv + bo)
//   logit_t = t@Wgt1^T + a@(Wgt2.Wvo)^T + (bgt + Wgt2.bvo)
//   refined_t = g*t + (1-g)*t_ctx, g = sigmoid(logit_t)   (audio swapped)
//
// Round-4 changes (driven by rocprof: gate FETCH 371 MB vs 136 ideal, 83% of
// dispatch time = HBM):
//   1. XCD swizzle: lid -> m=(lid>>6)*8+(lid&7), n=(lid>>3)&7. Same-m blocks
//      land on one XCD, 8 lids apart -> A-slice stays in that XCD's L2.
//   2. ctx GEMM fused into gate kernel (two accumulator chains) -> the 64 MB
//      f32 ctx intermediate never touches memory.
//
// Memory: ws = X (64MB) + persistent folded weights (~23.5MB) + biases.
//         d_out = bf16/transient prep scratch (~67MB, dead before fused
//         kernels write the f32 outputs in place).

typedef __attribute__((ext_vector_type(8))) short short8;
typedef __attribute__((ext_vector_type(4))) float floatx4;

__device__ __forceinline__ float bf2f(__hip_bfloat16 x) { return __bfloat162float(x); }

__device__ __forceinline__ void gl_lds16(const void* g, void* l) {
  __builtin_amdgcn_global_load_lds(
      (const __attribute__((address_space(1))) unsigned int*)g,
      (__attribute__((address_space(3))) unsigned int*)l,
      16, 0, 0);
}

// XCD-aware block swizzle. Requires gridDim.x == 8 (n-blocks), gridDim.y % 8 == 0
// (or gridDim.y == 8). All same-m blocks get lid % 8 == m % 8 -> same XCD,
// spaced 8 lids apart -> temporally adjacent on that XCD.
__device__ __forceinline__ void swizzle_mn(int& m_idx, int& n_idx) {
  const int lid = blockIdx.y * 8 + blockIdx.x;
  m_idx = (lid >> 6) * 8 + (lid & 7);
  n_idx = (lid >> 3) & 7;
}

// Strided f32 -> bf16 convert. One row per blockIdx.y, 4 cols per thread.
__global__ __launch_bounds__(256)
void cvt_kernel(const float* __restrict__ src, int sld,
                __hip_bfloat16* __restrict__ dst, int dld, int cols4) {
  const int r = blockIdx.y;
  const int c4 = blockIdx.x * 256 + threadIdx.x;
  if (c4 >= cols4) return;
  const float4 v = *(const float4*)(src + (size_t)r * sld + c4 * 4);
  union { __hip_bfloat16 h[4]; uint2 u; } o;
  o.h[0] = __float2bfloat16(v.x);
  o.h[1] = __float2bfloat16(v.y);
  o.h[2] = __float2bfloat16(v.z);
  o.h[3] = __float2bfloat16(v.w);
  *(uint2*)(dst + (size_t)r * dld + c4 * 4) = o.u;
}

// Transposed convert: dst[c][r] = bf16(src[r][c]), R=C=1024.
__global__ __launch_bounds__(256)
void cvt_t_kernel(const float* __restrict__ src, __hip_bfloat16* __restrict__ dst,
                  int R, int C) {
  __shared__ float tile[32][33];
  const int tx = threadIdx.x, ty = threadIdx.y;  // block (32, 8)
  const int bx = blockIdx.x * 32, by = blockIdx.y * 32;
#pragma unroll
  for (int i = 0; i < 32; i += 8)
    tile[ty + i][tx] = src[(size_t)(by + ty + i) * C + bx + tx];
  __syncthreads();
#pragma unroll
  for (int i = 0; i < 32; i += 8)
    dst[(size_t)(bx + ty + i) * R + by + tx] = __float2bfloat16(tile[tx][ty + i]);
}

// y[r] = sum_k W[r*ld + coff + k] * x[k] + b[r],  K = 1024. 4 rows/block.
__global__ __launch_bounds__(256)
void mv_kernel(const float* __restrict__ W, int ld, int coff,
               const float* __restrict__ x, const float* __restrict__ b,
               float* __restrict__ y) {
  const int lane = threadIdx.x & 63;
  const int row = blockIdx.x * 4 + (threadIdx.x >> 6);
  float acc = 0.f;
  for (int k = lane; k < 1024; k += 64)
    acc += W[(size_t)row * ld + coff + k] * x[k];
#pragma unroll
  for (int off = 32; off > 0; off >>= 1) acc += __shfl_down(acc, off);
  if (lane == 0) y[row] = acc + b[row];
}

// C = A @ W^T (+bias), bf16 out. A row-major (M x K) bf16, W (N x K) bf16.
// C[m*ldc + coff + n]. Used for projections and weight folds.
__global__ __launch_bounds__(256)
void gemm_bt_kernel(const __hip_bfloat16* __restrict__ A,
                    const __hip_bfloat16* __restrict__ W,
                    const float* __restrict__ bias,
                    __hip_bfloat16* __restrict__ C,
                    int K, int ldc, int coff) {
  constexpr int BK = 32;
  __shared__ __align__(16) __hip_bfloat16 lA[128 * BK];
  __shared__ __align__(16) __hip_bfloat16 lB[128 * BK];

  const int tid  = threadIdx.x;
  const int lane = tid & 63;
  const int wave = tid >> 6;
  const int wm = wave & 1;
  const int wn = wave >> 1;
  int m_idx, n_idx;
  swizzle_mn(m_idx, n_idx);
  const int m0 = m_idx * 128;
  const int n0 = n_idx * 128;

  floatx4 acc[4][4];
#pragma unroll
  for (int i = 0; i < 4; ++i)
#pragma unroll
    for (int j = 0; j < 4; ++j) {
      floatx4 z = {0.f, 0.f, 0.f, 0.f};
      acc[i][j] = z;
    }

  const int srow = tid >> 2;
  const int scol = (tid & 3) * 8;
  const int fr = lane & 15;
  const int fq = (lane >> 4) * 8;

  for (int k0 = 0; k0 < K; k0 += BK) {
    const __hip_bfloat16* srcA = A + (size_t)m0 * K + k0;
    const __hip_bfloat16* srcB = W + (size_t)n0 * K + k0;
#pragma unroll
    for (int p = 0; p < 2; ++p) {
      const int row = p * 64 + srow;
      gl_lds16(srcA + (size_t)row * K + scol, (char*)lA + p * 4096 + tid * 16);
      gl_lds16(srcB + (size_t)row * K + scol, (char*)lB + p * 4096 + tid * 16);
    }
    __syncthreads();

    short8 af[4], bfr[4];
#pragma unroll
    for (int i = 0; i < 4; ++i)
      af[i] = *(const short8*)((const short*)lA + (wm * 64 + i * 16 + fr) * BK + fq);
#pragma unroll
    for (int j = 0; j < 4; ++j)
      bfr[j] = *(const short8*)((const short*)lB + (wn * 64 + j * 16 + fr) * BK + fq);
#pragma unroll
    for (int i = 0; i < 4; ++i)
#pragma unroll
      for (int j = 0; j < 4; ++j)
        acc[i][j] = __builtin_amdgcn_mfma_f32_16x16x32_bf16(af[i], bfr[j], acc[i][j], 0, 0, 0);
    __syncthreads();
  }

  const int col = lane & 15;
  const int rq  = (lane >> 4) * 4;
#pragma unroll
  for (int j = 0; j < 4; ++j) {
    const int n = n0 + wn * 64 + j * 16 + col;
    const float bv = bias ? bias[n] : 0.f;
#pragma unroll
    for (int i = 0; i < 4; ++i)
#pragma unroll
      for (int r = 0; r < 4; ++r) {
        const int m = m0 + wm * 64 + i * 16 + rq + r;
        C[(size_t)m * ldc + coff + n] = __float2bfloat16(acc[i][j][r] + bv);
      }
  }
}

// Fused ctx + gate kernel (per modality), N = 1024:
//   logit = Xs@Wcat[:, :1024]^T + Xo@Wcat[:, 1024:]^T + bg
//   ctx   = Xo@Wvo^T + bvo
//   out[m,n] = g*Xs[m,n] + (1-g)*ctx,  g = sigmoid(logit)     (f32 out)
__global__ __launch_bounds__(256)
void fused_gate_kernel(const __hip_bfloat16* __restrict__ Xs,
                       const __hip_bfloat16* __restrict__ Xo,
                       const __hip_bfloat16* __restrict__ Wcat,  // 1024 x 2048
                       const __hip_bfloat16* __restrict__ Wvo,   // 1024 x 1024
                       const float* __restrict__ bg,
                       const float* __restrict__ bvo,
                       float* __restrict__ out) {
  constexpr int BK = 32;
  __shared__ __align__(16) __hip_bfloat16 lA[128 * BK];
  __shared__ __align__(16) __hip_bfloat16 lB[128 * BK];
  __shared__ __align__(16) __hip_bfloat16 lC[128 * BK];

  const int tid  = threadIdx.x;
  const int lane = tid & 63;
  const int wave = tid >> 6;
  const int wm = wave & 1;
  const int wn = wave >> 1;
  int m_idx, n_idx;
  swizzle_mn(m_idx, n_idx);
  const int m0 = m_idx * 128;
  const int n0 = n_idx * 128;

  floatx4 accL[4][4], accC[4][4];
#pragma unroll
  for (int i = 0; i < 4; ++i)
#pragma unroll
    for (int j = 0; j < 4; ++j) {
      floatx4 z = {0.f, 0.f, 0.f, 0.f};
      accL[i][j] = z;
      accC[i][j] = z;
    }

  const int srow = tid >> 2;
  const int scol = (tid & 3) * 8;
  const int fr = lane & 15;
  const int fq = (lane >> 4) * 8;

  // ---- phase 1: k in [0,1024), A = Xs, logit += Xs @ Wgt1^T ----
  for (int k0 = 0; k0 < 1024; k0 += BK) {
    const __hip_bfloat16* srcA = Xs + (size_t)m0 * 1024 + k0;
    const __hip_bfloat16* srcB = Wcat + (size_t)n0 * 2048 + k0;
#pragma unroll
    for (int p = 0; p < 2; ++p) {
      const int row = p * 64 + srow;
      gl_lds16(srcA + (size_t)row * 1024 + scol, (char*)lA + p * 4096 + tid * 16);
      gl_lds16(srcB + (size_t)row * 2048 + scol, (char*)lB + p * 4096 + tid * 16);
    }
    __syncthreads();

    short8 af[4], bfr[4];
#pragma unroll
    for (int i = 0; i < 4; ++i)
      af[i] = *(const short8*)((const short*)lA + (wm * 64 + i * 16 + fr) * BK + fq);
#pragma unroll
    for (int j = 0; j < 4; ++j)
      bfr[j] = *(const short8*)((const short*)lB + (wn * 64 + j * 16 + fr) * BK + fq);
#pragma unroll
    for (int i = 0; i < 4; ++i)
#pragma unroll
      for (int j = 0; j < 4; ++j)
        accL[i][j] = __builtin_amdgcn_mfma_f32_16x16x32_bf16(af[i], bfr[j], accL[i][j], 0, 0, 0);
    __syncthreads();
  }

  // ---- phase 2: k in [0,1024), A = Xo; logit += Xo @ (Wgt2.Wvo)^T ; ctx += Xo @ Wvo^T ----
  for (int k0 = 0; k0 < 1024; k0 += BK) {
    const __hip_bfloat16* srcA = Xo + (size_t)m0 * 1024 + k0;
    const __hip_bfloat16* srcB = Wcat + (size_t)n0 * 2048 + 1024 + k0;
    const __hip_bfloat16* srcC = Wvo + (size_t)n0 * 1024 + k0;
#pragma unroll
    for (int p = 0; p < 2; ++p) {
      const int row = p * 64 + srow;
      gl_lds16(srcA + (size_t)row * 1024 + scol, (char*)lA + p * 4096 + tid * 16);
      gl_lds16(srcB + (size_t)row * 2048 + scol, (char*)lB + p * 4096 + tid * 16);
      gl_lds16(srcC + (size_t)row * 1024 + scol, (char*)lC + p * 4096 + tid * 16);
    }
    __syncthreads();

    short8 af[4], bfr[4], cfr[4];
#pragma unroll
    for (int i = 0; i < 4; ++i)
      af[i] = *(const short8*)((const short*)lA + (wm * 64 + i * 16 + fr) * BK + fq);
#pragma unroll
    for (int j = 0; j < 4; ++j) {
      bfr[j] = *(const short8*)((const short*)lB + (wn * 64 + j * 16 + fr) * BK + fq);
      cfr[j] = *(const short8*)((const short*)lC + (wn * 64 + j * 16 + fr) * BK + fq);
    }
#pragma unroll
    for (int i = 0; i < 4; ++i)
#pragma unroll
      for (int j = 0; j < 4; ++j) {
        accL[i][j] = __builtin_amdgcn_mfma_f32_16x16x32_bf16(af[i], bfr[j], accL[i][j], 0, 0, 0);
        accC[i][j] = __builtin_amdgcn_mfma_f32_16x16x32_bf16(af[i], cfr[j], accC[i][j], 0, 0, 0);
      }
    __syncthreads();
  }

  // epilogue: D mapping col = lane&15, row = (lane>>4)*4 + reg
  const int col = lane & 15;
  const int rq  = (lane >> 4) * 4;
#pragma unroll
  for (int j = 0; j < 4; ++j) {
    const int n = n0 + wn * 64 + j * 16 + col;
    const float bgv = bg[n];
    const float bcv = bvo[n];
#pragma unroll
    for (int i = 0; i < 4; ++i)
#pragma unroll
      for (int r = 0; r < 4; ++r) {
        const int m = m0 + wm * 64 + i * 16 + rq + r;
        const size_t idx = (size_t)m * 1024 + n;
        const float lg = accL[i][j][r] + bgv;
        const float cv = accC[i][j][r] + bcv;
        const float xv = bf2f(Xs[idx]);
        const float g = 1.f / (1.f + __expf(-lg));
        out[idx] = g * xv + (1.f - g) * cv;
      }
  }
}

extern "C" void kernel_launch(void* const* d_in, const int* in_sizes, int n_in,
                              void* d_out, int out_size, void* d_ws, size_t ws_size,
                              hipStream_t stream) {
  (void)in_sizes; (void)n_in; (void)out_size; (void)ws_size;

  const float* text  = (const float*)d_in[0];
  const float* audio = (const float*)d_in[1];
  const float* Wt  = (const float*)d_in[2];
  const float* bt  = (const float*)d_in[3];
  const float* Wa  = (const float*)d_in[4];
  const float* ba  = (const float*)d_in[5];
  // d_in[6..9] = Wq,bq,Wk,bk: dead (softmax over single kv slot == 1)
  const float* Wv  = (const float*)d_in[10];
  const float* bv  = (const float*)d_in[11];
  const float* Wo  = (const float*)d_in[12];
  const float* bo  = (const float*)d_in[13];
  const float* Wgt = (const float*)d_in[14];
  const float* bgt = (const float*)d_in[15];
  const float* Wga = (const float*)d_in[16];
  const float* bga = (const float*)d_in[17];

  const size_t BE = 16384ull * 1024;
  const size_t M1 = 1024ull * 1024;
  float* out = (float*)d_out;

  // ws (persistent across chain): ~87.5 MB  (proven-safe budget < 92 MB)
  __hip_bfloat16* p = (__hip_bfloat16*)d_ws;
  __hip_bfloat16* X       = p; p += 2 * BE;        // [t ; a]
  __hip_bfloat16* Wt_b    = p; p += 768ull * 1024;
  __hip_bfloat16* Wa_b    = p; p += M1;
  __hip_bfloat16* Wo_b    = p; p += M1;
  __hip_bfloat16* Wvo_b   = p; p += M1;
  __hip_bfloat16* Wgt_cat = p; p += 2 * M1;        // [Wgt1 | Wgt2.Wvo], ld 2048
  __hip_bfloat16* Wga_cat = p; p += 2 * M1;
  float* bvo  = (float*)p;
  float* bgtp = bvo + 1024;
  float* bgap = bvo + 2048;

  // d_out transient scratch (all dead before fused kernels write f32 out)
  __hip_bfloat16* scr     = (__hip_bfloat16*)d_out;
  __hip_bfloat16* text_b  = scr;                          // 16384x768
  __hip_bfloat16* audio_b = scr + 16384ull * 768;         // 16384x1024
  __hip_bfloat16* WvT_b   = audio_b + BE;                 // 4 transient 1024^2 tiles
  __hip_bfloat16* WvoT_b  = WvT_b + M1;
  __hip_bfloat16* Wgt2_b  = WvoT_b + M1;
  __hip_bfloat16* Wga2_b  = Wgt2_b + M1;                  // ends at ~67 MB < 128 MB

  dim3 blk(256, 1, 1);

  // ---- converts ----
  cvt_kernel<<<dim3(1, 16384), blk, 0, stream>>>(text, 768, text_b, 768, 192);
  cvt_kernel<<<dim3(1, 16384), blk, 0, stream>>>(audio, 1024, audio_b, 1024, 256);
  cvt_kernel<<<dim3(1, 768), blk, 0, stream>>>(Wt, 1024, Wt_b, 1024, 256);
  cvt_kernel<<<dim3(1, 1024), blk, 0, stream>>>(Wa, 1024, Wa_b, 1024, 256);
  cvt_kernel<<<dim3(1, 1024), blk, 0, stream>>>(Wo, 1024, Wo_b, 1024, 256);
  cvt_t_kernel<<<dim3(32, 32), dim3(32, 8), 0, stream>>>(Wv, WvT_b, 1024, 1024);
  cvt_kernel<<<dim3(1, 1024), blk, 0, stream>>>(Wgt, 2048, Wgt_cat, 2048, 256);        // Wgt1
  cvt_kernel<<<dim3(1, 1024), blk, 0, stream>>>(Wgt + 1024, 2048, Wgt2_b, 1024, 256);  // Wgt2
  cvt_kernel<<<dim3(1, 1024), blk, 0, stream>>>(Wga, 2048, Wga_cat, 2048, 256);
  cvt_kernel<<<dim3(1, 1024), blk, 0, stream>>>(Wga + 1024, 2048, Wga2_b, 1024, 256);

  // ---- bias folds (f32) ----
  mv_kernel<<<dim3(256), blk, 0, stream>>>(Wo, 1024, 0, bv, bo, bvo);         // bvo = Wo.bv + bo
  mv_kernel<<<dim3(256), blk, 0, stream>>>(Wgt, 2048, 1024, bvo, bgt, bgtp);  // bgt' = Wgt2.bvo + bgt
  mv_kernel<<<dim3(256), blk, 0, stream>>>(Wga, 2048, 1024, bvo, bga, bgap);

  // ---- weight folds (1024^3 bf16 GEMMs) ----
  dim3 gw(8, 8);
  // Wvo[n,k]  = sum_m Wo[n,m] WvT[k,m]
  gemm_bt_kernel<<<gw, blk, 0, stream>>>(Wo_b, WvT_b, nullptr, Wvo_b, 1024, 1024, 0);
  // WvoT[k,n] = sum_m WvT[k,m] Wo[n,m]
  gemm_bt_kernel<<<gw, blk, 0, stream>>>(WvT_b, Wo_b, nullptr, WvoT_b, 1024, 1024, 0);
  // Wg_cat[:,1024+k] = (Wg2.Wvo)[n,k] = sum_m Wg2[n,m] WvoT[k,m]
  gemm_bt_kernel<<<gw, blk, 0, stream>>>(Wgt2_b, WvoT_b, nullptr, Wgt_cat, 1024, 2048, 1024);
  gemm_bt_kernel<<<gw, blk, 0, stream>>>(Wga2_b, WvoT_b, nullptr, Wga_cat, 1024, 2048, 1024);

  // ---- projections ----
  dim3 g1(8, 128);
  gemm_bt_kernel<<<g1, blk, 0, stream>>>(text_b, Wt_b, bt, X, 768, 1024, 0);
  gemm_bt_kernel<<<g1, blk, 0, stream>>>(audio_b, Wa_b, ba, X + BE, 1024, 1024, 0);

  // ---- fused ctx + gate (f32 out, in final position) ----
  fused_gate_kernel<<<g1, blk, 0, stream>>>(X, X + BE, Wgt_cat, Wvo_b, bgtp, bvo, out);
  fused_gate_kernel<<<g1, blk, 0, stream>>>(X + BE, X, Wga_cat, Wvo_b, bgap, bvo, out + BE);
}